// Round 10
// baseline (204.788 us; speedup 1.0000x reference)
//
#include <hip/hip_runtime.h>
#include <hip/hip_bf16.h>

#define NUM_D1 270
#define NUM_B  128
#define NUM_C  273
#define NUM_T  1024
#define KL     1024      // K*K = 32*32
#define TW     320       // trig table padded width
#define CP     288       // padded C for a[] (9 * 32)
#define CW     296       // wg / X-LDS row stride in elems (592 B; granule 37 odd -> conflict-free)
#define ROWB   (CW * 2)  // 592 bytes

#define WT_BYTES (144 * ROWB)                 // 85,248
#define XB_BYTES (64 * ROWB)                  // 37,888
#define LDS6_TOTAL (WT_BYTES + 2 * XB_BYTES)  // 161,024 <= 163,840

typedef float f32x4 __attribute__((ext_vector_type(4)));
typedef __bf16 bf16x8 __attribute__((ext_vector_type(8)));

// Barrier with compiler memory fences on BOTH sides: raw s_barrier is not an
// IR-level fence; without the trailing "memory" asm, next-iteration ds_reads
// can hoist above the barrier (r8's replay race).
#define FENCED_BARRIER()                                     \
  do {                                                       \
    asm volatile("s_waitcnt lgkmcnt(0)" ::: "memory");       \
    __builtin_amdgcn_s_barrier();                            \
    asm volatile("" ::: "memory");                           \
    __builtin_amdgcn_sched_barrier(0);                       \
  } while (0)

static __device__ __forceinline__ unsigned short f2bf(float f) {
  unsigned u = __float_as_uint(f);
  unsigned r = (u + 0x7fffu + ((u >> 16) & 1u)) >> 16;   // RNE
  return (unsigned short)r;
}

static __device__ __forceinline__ unsigned cvt_pk_bf16(float lo, float hi) {
  unsigned r;
  asm("v_cvt_pk_bf16_f32 %0, %1, %2" : "=v"(r) : "v"(lo), "v"(hi));
  return r;
}

// Kernel 0: trig table (cos,sin) interleaved float2
__global__ __launch_bounds__(256) void k_trig(const float* __restrict__ loc,
                                              float2* __restrict__ tab) {
  int idx = blockIdx.x * 256 + threadIdx.x;   // 0 .. 1024*320-1
  int kl = idx / TW;
  int c  = idx - kl * TW;
  float cv = 0.f, sv = 0.f;
  if (c < NUM_C) {
    float x = loc[2 * c], y = loc[2 * c + 1];
    float kf = (float)(kl >> 5), lf = (float)(kl & 31);
    float ph = 6.283185307179586f * (kf * x + lf * y);
    sincosf(ph, &sv, &cv);
  }
  tab[idx] = make_float2(cv, sv);
}

// Kernel 1: a[j,c] = sum_kl z_re[j,kl]*cos[kl,c] + z_im[j,kl]*sin[kl,c]
__global__ __launch_bounds__(1024) void k_agemm(const float* __restrict__ z_re,
                                                const float* __restrict__ z_im,
                                                const float2* __restrict__ tab,
                                                float* __restrict__ a) {
  __shared__ float sm[4][8][64];
  int tid = threadIdx.x;
  int lane = tid & 63;
  int g = tid >> 6;            // 0..15
  int p = g >> 3;              // 0..1
  int q = g & 7;               // 0..7
  int jb = blockIdx.x;         // 0..67
  int cb = blockIdx.y;         // 0..4
  int c = cb * 64 + lane;      // < 320, in-bounds of padded table
  int j_a = jb * 4 + p;        // <= 269
  int j_b = j_a + 2;           // <= 271
  int jeb = (j_b < NUM_D1) ? j_b : 0;
  const float* zr0 = z_re + (size_t)j_a * KL;
  const float* zi0 = z_im + (size_t)j_a * KL;
  const float* zr1 = z_re + (size_t)jeb * KL;
  const float* zi1 = z_im + (size_t)jeb * KL;
  float a0 = 0.f, a1 = 0.f;
  int k0 = q * 128;
  #pragma unroll 4
  for (int kk = k0; kk < k0 + 128; ++kk) {
    float2 cs = tab[kk * TW + c];
    a0 = fmaf(zr0[kk], cs.x, a0);
    a0 = fmaf(zi0[kk], cs.y, a0);
    a1 = fmaf(zr1[kk], cs.x, a1);
    a1 = fmaf(zi1[kk], cs.y, a1);
  }
  sm[p][q][lane] = a0;
  sm[p + 2][q][lane] = a1;
  __syncthreads();
  if (tid < 256) {
    int jl = tid >> 6;          // 0..3
    int l2 = tid & 63;
    int j = jb * 4 + jl;
    int c2 = cb * 64 + l2;
    float s = 0.f;
    #pragma unroll
    for (int qq = 0; qq < 8; ++qq) s += sm[jl][qq][l2];
    if (j < NUM_D1 && c2 < NUM_C) a[j * CP + c2] = s;
  }
}

// Kernel 2: w[j,:] = softmax_c(a[j,:]) -> bf16 into wg[288 rows][CW=296 stride], zero-padded
__global__ __launch_bounds__(256) void k_softmax(const float* __restrict__ a,
                                                 unsigned short* __restrict__ wg) {
  int wv = threadIdx.x >> 6;
  int lane = threadIdx.x & 63;
  int j = blockIdx.x * 4 + wv;   // < 288 (grid 72)
  if (j >= NUM_D1) {
    for (int c = lane; c < CW; c += 64) wg[j * CW + c] = 0;
    return;
  }
  float e[5];
  float s = 0.f;
  #pragma unroll
  for (int qq = 0; qq < 5; ++qq) {
    int c = qq * 64 + lane;
    float v = 0.f;
    if (c < NUM_C) v = expf(a[j * CP + c]);
    e[qq] = v;
    s += v;
  }
  #pragma unroll
  for (int o = 32; o > 0; o >>= 1) s += __shfl_xor(s, o, 64);
  float inv = 1.0f / s;
  #pragma unroll
  for (int qq = 0; qq < 5; ++qq) {
    int c = qq * 64 + lane;
    if (c < CW) wg[j * CW + c] = (c < NUM_C) ? f2bf(e[qq] * inv) : (unsigned short)0;
  }
}

// Kernel 3 (k_out6): producer/consumer wave specialization.
// 768 thr / 12 waves: waves 0-2 = consumers (jq = wave; 3 jt x 4 tt tiles each),
// waves 3-11 = producers (576 threads stage 64t x 288c X^T tiles, double-buffered).
// W-half resident in LDS; fenced barriers; producer loads 2 tiles ahead.
__global__ __launch_bounds__(768, 3) void k_out6(const float* __restrict__ X,
                                                 const unsigned short* __restrict__ wg,
                                                 float* __restrict__ out) {
  extern __shared__ char lds[];
  char* WTb = lds;
  char* XA  = lds + WT_BYTES;
  char* XBf = lds + WT_BYTES + XB_BYTES;

  const int tid = threadIdx.x;
  const int wv = tid >> 6, lane = tid & 63;
  const int rlo = lane & 15, kg = lane >> 4;
  const bool isProd = (wv >= 3);

  // XCD-aware mapping: (jh=0,1) of each b on the same XCD's L2
  const int lin = blockIdx.x;          // 0..255
  const int xcd = lin & 7, slot = lin >> 3;
  const int jh = slot & 1;
  const int b  = xcd * 16 + (slot >> 1);
  const float* Xb = X + (size_t)b * (NUM_C * NUM_T);

  // producer geometry: s = 0..575 -> t4 = s/36 (0..15), co = s%36 (c-octet)
  const int s  = isProd ? (tid - 192) : 0;
  const int t4 = s / 36;
  const int co = s - t4 * 36;

  f32x4 va[8];

  // ---- prologue ----
  if (isProd) {
    #pragma unroll
    for (int e = 0; e < 8; ++e) {
      int c = co * 8 + e;
      if (c < NUM_C) va[e] = *(const f32x4*)(Xb + (size_t)c * NUM_T + t4 * 4);
      else { va[e][0] = va[e][1] = va[e][2] = va[e][3] = 0.f; }
    }
  }
  {
    const char* wsrc = (const char*)wg + (size_t)jh * WT_BYTES;
    #pragma unroll
    for (int i = 0; i < 7; ++i) {
      int off = (tid + i * 768) * 16;
      if (off < WT_BYTES) *(uint4*)(WTb + off) = *(const uint4*)(wsrc + off);
    }
  }
  if (isProd) {
    // write tile 0 (compiler inserts vmcnt waits on va)
    #pragma unroll
    for (int f = 0; f < 4; ++f) {
      uint4 w;
      w.x = cvt_pk_bf16(va[0][f], va[1][f]);
      w.y = cvt_pk_bf16(va[2][f], va[3][f]);
      w.z = cvt_pk_bf16(va[4][f], va[5][f]);
      w.w = cvt_pk_bf16(va[6][f], va[7][f]);
      *(uint4*)(XA + (t4 * 4 + f) * ROWB + co * 16) = w;
    }
    // issue tile 1 loads (stay in flight across the barrier)
    #pragma unroll
    for (int e = 0; e < 8; ++e) {
      int c = co * 8 + e;
      if (c < NUM_C) va[e] = *(const f32x4*)(Xb + (size_t)c * NUM_T + 64 + t4 * 4);
      else { va[e][0] = va[e][1] = va[e][2] = va[e][3] = 0.f; }
    }
  }
  FENCED_BARRIER();

  const int jq = wv;   // consumers only (0..2)

  for (int it = 0; it < 16; ++it) {
    const int t0 = it * 64;
    char* xcur = (it & 1) ? XBf : XA;
    char* xnxt = (it & 1) ? XA : XBf;

    if (!isProd) {
      // ---- consumer: 63 LDS b128 reads, 108 MFMA, 48 stores ----
      f32x4 acc[3][4];
      #pragma unroll
      for (int jt = 0; jt < 3; ++jt)
        #pragma unroll
        for (int tt = 0; tt < 4; ++tt)
          acc[jt][tt][0] = acc[jt][tt][1] = acc[jt][tt][2] = acc[jt][tt][3] = 0.f;

      const char* wbase = WTb + (size_t)(jq * 48 + rlo) * ROWB + kg * 16;
      const char* xbase = xcur + (size_t)rlo * ROWB + kg * 16;

      #pragma unroll
      for (int ks = 0; ks < 9; ++ks) {
        bf16x8 a0 = *(const bf16x8*)(wbase + 0 * 16 * ROWB + ks * 64);
        bf16x8 a1 = *(const bf16x8*)(wbase + 1 * 16 * ROWB + ks * 64);
        bf16x8 a2 = *(const bf16x8*)(wbase + 2 * 16 * ROWB + ks * 64);
        #pragma unroll
        for (int tt = 0; tt < 4; ++tt) {
          bf16x8 bq = *(const bf16x8*)(xbase + tt * 16 * ROWB + ks * 64);
          acc[0][tt] = __builtin_amdgcn_mfma_f32_16x16x32_bf16(a0, bq, acc[0][tt], 0, 0, 0);
          acc[1][tt] = __builtin_amdgcn_mfma_f32_16x16x32_bf16(a1, bq, acc[1][tt], 0, 0, 0);
          acc[2][tt] = __builtin_amdgcn_mfma_f32_16x16x32_bf16(a2, bq, acc[2][tt], 0, 0, 0);
        }
      }

      #pragma unroll
      for (int jt = 0; jt < 3; ++jt) {
        int jb2 = jh * 144 + (jq * 3 + jt) * 16 + kg * 4;
        #pragma unroll
        for (int tt = 0; tt < 4; ++tt) {
          #pragma unroll
          for (int r = 0; r < 4; ++r) {
            int j = jb2 + r;
            if (j < NUM_D1)
              out[((size_t)b * NUM_D1 + j) * NUM_T + t0 + tt * 16 + rlo] = acc[jt][tt][r];
          }
        }
      }
    } else {
      // ---- producer: write tile it+1, issue loads for tile it+2 ----
      if (it < 15) {
        #pragma unroll
        for (int f = 0; f < 4; ++f) {
          uint4 w;
          w.x = cvt_pk_bf16(va[0][f], va[1][f]);
          w.y = cvt_pk_bf16(va[2][f], va[3][f]);
          w.z = cvt_pk_bf16(va[4][f], va[5][f]);
          w.w = cvt_pk_bf16(va[6][f], va[7][f]);
          *(uint4*)(xnxt + (t4 * 4 + f) * ROWB + co * 16) = w;
        }
        if (it < 14) {
          #pragma unroll
          for (int e = 0; e < 8; ++e) {
            int c = co * 8 + e;
            if (c < NUM_C) va[e] = *(const f32x4*)(Xb + (size_t)c * NUM_T + t0 + 128 + t4 * 4);
            else { va[e][0] = va[e][1] = va[e][2] = va[e][3] = 0.f; }
          }
        }
      }
    }

    FENCED_BARRIER();
  }
}

extern "C" void kernel_launch(void* const* d_in, const int* in_sizes, int n_in,
                              void* d_out, int out_size, void* d_ws, size_t ws_size,
                              hipStream_t stream) {
  const float* X   = (const float*)d_in[0];
  const float* loc = (const float*)d_in[1];
  const float* zre = (const float*)d_in[2];
  const float* zim = (const float*)d_in[3];
  float* out = (float*)d_out;
  char* ws = (char*)d_ws;
  float2* tab = (float2*)(ws);                              // 2,621,440 B
  float* a    = (float*)(ws + 2621440);                     // 313,344 B
  unsigned short* wgp = (unsigned short*)(ws + 2934784);    // [288][296] bf16 = 170,496 B

  (void)hipFuncSetAttribute((const void*)k_out6,
                            hipFuncAttributeMaxDynamicSharedMemorySize, LDS6_TOTAL);

  hipLaunchKernelGGL(k_trig,    dim3(1280),   dim3(256),  0, stream, loc, tab);
  hipLaunchKernelGGL(k_agemm,   dim3(68, 5),  dim3(1024), 0, stream, zre, zim, tab, a);
  hipLaunchKernelGGL(k_softmax, dim3(72),     dim3(256),  0, stream, a, wgp);
  hipLaunchKernelGGL(k_out6,    dim3(256),    dim3(768),  LDS6_TOTAL, stream, X, wgp, out);
}

// Round 11
// 182.971 us; speedup vs baseline: 1.1192x; 1.1192x over previous
//
#include <hip/hip_runtime.h>
#include <hip/hip_bf16.h>

#define NUM_D1 270
#define NUM_B  128
#define NUM_C  273
#define NUM_T  1024
#define KL     1024      // K*K = 32*32
#define TW     320       // trig table padded width
#define CP     288       // padded C for a[] (9 * 32)
#define CW     292       // wg / X-LDS row stride in elems (584 B = 146 dw == 18 mod 32; 2-way free at 32 rows)
#define ROWB   (CW * 2)  // 584 bytes

#define XT_BYTES (32 * ROWB)        // 18,688  (one 32-t X^T tile)
#define LDS7_TOTAL (2 * XT_BYTES)   // 37,376

typedef float f32x4 __attribute__((ext_vector_type(4)));
typedef float f32x16 __attribute__((ext_vector_type(16)));
typedef __bf16 bf16x8 __attribute__((ext_vector_type(8)));

// Barrier with compiler memory fences on BOTH sides (r8's replay race fix).
#define FENCED_BARRIER()                                     \
  do {                                                       \
    asm volatile("s_waitcnt lgkmcnt(0)" ::: "memory");       \
    __builtin_amdgcn_s_barrier();                            \
    asm volatile("" ::: "memory");                           \
    __builtin_amdgcn_sched_barrier(0);                       \
  } while (0)

static __device__ __forceinline__ unsigned short f2bf(float f) {
  unsigned u = __float_as_uint(f);
  unsigned r = (u + 0x7fffu + ((u >> 16) & 1u)) >> 16;   // RNE
  return (unsigned short)r;
}

static __device__ __forceinline__ unsigned cvt_pk_bf16(float lo, float hi) {
  unsigned r;
  asm("v_cvt_pk_bf16_f32 %0, %1, %2" : "=v"(r) : "v"(lo), "v"(hi));
  return r;
}

// Kernel 0: trig table (cos,sin) interleaved float2
__global__ __launch_bounds__(256) void k_trig(const float* __restrict__ loc,
                                              float2* __restrict__ tab) {
  int idx = blockIdx.x * 256 + threadIdx.x;   // 0 .. 1024*320-1
  int kl = idx / TW;
  int c  = idx - kl * TW;
  float cv = 0.f, sv = 0.f;
  if (c < NUM_C) {
    float x = loc[2 * c], y = loc[2 * c + 1];
    float kf = (float)(kl >> 5), lf = (float)(kl & 31);
    float ph = 6.283185307179586f * (kf * x + lf * y);
    sincosf(ph, &sv, &cv);
  }
  tab[idx] = make_float2(cv, sv);
}

// Kernel 1: a[j,c] = sum_kl z_re[j,kl]*cos[kl,c] + z_im[j,kl]*sin[kl,c]
__global__ __launch_bounds__(1024) void k_agemm(const float* __restrict__ z_re,
                                                const float* __restrict__ z_im,
                                                const float2* __restrict__ tab,
                                                float* __restrict__ a) {
  __shared__ float sm[4][8][64];
  int tid = threadIdx.x;
  int lane = tid & 63;
  int g = tid >> 6;            // 0..15
  int p = g >> 3;              // 0..1
  int q = g & 7;               // 0..7
  int jb = blockIdx.x;         // 0..67
  int cb = blockIdx.y;         // 0..4
  int c = cb * 64 + lane;      // < 320, in-bounds of padded table
  int j_a = jb * 4 + p;        // <= 269
  int j_b = j_a + 2;           // <= 271
  int jeb = (j_b < NUM_D1) ? j_b : 0;
  const float* zr0 = z_re + (size_t)j_a * KL;
  const float* zi0 = z_im + (size_t)j_a * KL;
  const float* zr1 = z_re + (size_t)jeb * KL;
  const float* zi1 = z_im + (size_t)jeb * KL;
  float a0 = 0.f, a1 = 0.f;
  int k0 = q * 128;
  #pragma unroll 4
  for (int kk = k0; kk < k0 + 128; ++kk) {
    float2 cs = tab[kk * TW + c];
    a0 = fmaf(zr0[kk], cs.x, a0);
    a0 = fmaf(zi0[kk], cs.y, a0);
    a1 = fmaf(zr1[kk], cs.x, a1);
    a1 = fmaf(zi1[kk], cs.y, a1);
  }
  sm[p][q][lane] = a0;
  sm[p + 2][q][lane] = a1;
  __syncthreads();
  if (tid < 256) {
    int jl = tid >> 6;          // 0..3
    int l2 = tid & 63;
    int j = jb * 4 + jl;
    int c2 = cb * 64 + l2;
    float s = 0.f;
    #pragma unroll
    for (int qq = 0; qq < 8; ++qq) s += sm[jl][qq][l2];
    if (j < NUM_D1 && c2 < NUM_C) a[j * CP + c2] = s;
  }
}

// Kernel 2: w[j,:] = softmax_c(a[j,:]) -> bf16 into wg[288 rows][CW=292 stride], zero-padded
__global__ __launch_bounds__(256) void k_softmax(const float* __restrict__ a,
                                                 unsigned short* __restrict__ wg) {
  int wv = threadIdx.x >> 6;
  int lane = threadIdx.x & 63;
  int j = blockIdx.x * 4 + wv;   // < 288 (grid 72)
  if (j >= NUM_D1) {
    for (int c = lane; c < CW; c += 64) wg[j * CW + c] = 0;
    return;
  }
  float e[5];
  float s = 0.f;
  #pragma unroll
  for (int qq = 0; qq < 5; ++qq) {
    int c = qq * 64 + lane;
    float v = 0.f;
    if (c < NUM_C) v = expf(a[j * CP + c]);
    e[qq] = v;
    s += v;
  }
  #pragma unroll
  for (int o = 32; o > 0; o >>= 1) s += __shfl_xor(s, o, 64);
  float inv = 1.0f / s;
  #pragma unroll
  for (int qq = 0; qq < 5; ++qq) {
    int c = qq * 64 + lane;
    if (c < CW) wg[j * CW + c] = (c < NUM_C) ? f2bf(e[qq] * inv) : (unsigned short)0;
  }
}

// Kernel 3 (k_out7): 32x32x16 MFMA, W register-resident.
// 576 thr / 9 waves; wave wv owns j32-tile wv (covers all 288 j). W-fragments:
// 18 x bf16x8 = 72 VGPR loaded from global ONCE (keep-alive asm). LDS = only the
// double-buffered 32t x 288c X^T tile (37 KB). Grid (2 t-halves x 128 b) = 256
// blocks; per-block 16 iterations of 32 t. A=X (LDS), B=W (regs):
// D col=lane&31 -> j, row=(reg&3)+8*(reg>>2)+4*(lane>>5) -> t  => f32x4 stores.
__global__ __launch_bounds__(576, 2) void k_out7(const float* __restrict__ X,
                                                 const unsigned short* __restrict__ wg,
                                                 float* __restrict__ out) {
  extern __shared__ char lds[];
  char* XA  = lds;
  char* XB2 = lds + XT_BYTES;

  const int tid = threadIdx.x;
  const int wv = tid / 64, lane = tid & 63;
  const int nlo = lane & 31, hi = lane >> 5;
  const int th = blockIdx.x >> 7;       // 0..1 (t-half)
  const int b  = blockIdx.x & 127;      // 0..127
  const int tbase = th * 512;
  const float* Xb = X + (size_t)b * (NUM_C * NUM_T);

  // staging geometry: all 576 threads; c-quad c4 = tid>>3 (0..71), t-quad t4 = tid&7
  const int c4 = tid >> 3;
  const int t4 = tid & 7;

  // ---- W fragments (B operand), once per block: row j = wv*32 + nlo,
  //      k = ks*16 + hi*8 + (0..7)  -> byte ks*32 + hi*16
  bf16x8 wfr[18];
  {
    const char* wrow = (const char*)wg + (size_t)(wv * 32 + nlo) * ROWB + hi * 16;
    #pragma unroll
    for (int ks = 0; ks < 18; ++ks) {
      wfr[ks] = *(const bf16x8*)(wrow + ks * 32);
      asm volatile("" : "+v"(wfr[ks]));   // opaque def: cannot be sunk/rematerialized
    }
  }

  f32x4 va[4];

  // ---- prologue: tile 0 load -> write XA; issue tile 1 loads ----
  #pragma unroll
  for (int e = 0; e < 4; ++e) {
    int c = c4 * 4 + e;
    if (c < NUM_C) va[e] = *(const f32x4*)(Xb + (size_t)c * NUM_T + tbase + t4 * 4);
    else { va[e][0] = va[e][1] = va[e][2] = va[e][3] = 0.f; }
  }
  #pragma unroll
  for (int f = 0; f < 4; ++f) {
    uint2 w;
    w.x = cvt_pk_bf16(va[0][f], va[1][f]);
    w.y = cvt_pk_bf16(va[2][f], va[3][f]);
    *(uint2*)(XA + (t4 * 4 + f) * ROWB + c4 * 8) = w;
  }
  #pragma unroll
  for (int e = 0; e < 4; ++e) {
    int c = c4 * 4 + e;
    if (c < NUM_C) va[e] = *(const f32x4*)(Xb + (size_t)c * NUM_T + tbase + 32 + t4 * 4);
    else { va[e][0] = va[e][1] = va[e][2] = va[e][3] = 0.f; }
  }
  FENCED_BARRIER();

  const int j = wv * 32 + nlo;
  float* orow_base = out + ((size_t)b * NUM_D1 + j) * NUM_T + 4 * hi;

  for (int it = 0; it < 16; ++it) {
    const int t0 = tbase + it * 32;
    char* xcur = (it & 1) ? XB2 : XA;
    char* xnxt = (it & 1) ? XA : XB2;

    // ---- compute: 18 ds_read_b128 (A=X frags) + 18 MFMA into one f32x16 ----
    f32x16 acc;
    #pragma unroll
    for (int r = 0; r < 16; ++r) acc[r] = 0.f;
    const char* xrow = xcur + (size_t)nlo * ROWB + hi * 16;
    #pragma unroll
    for (int ks = 0; ks < 18; ++ks) {
      bf16x8 xf = *(const bf16x8*)(xrow + ks * 32);
      acc = __builtin_amdgcn_mfma_f32_32x32x16_bf16(xf, wfr[ks], acc, 0, 0, 0);
    }

    // ---- stores: 4 x f32x4, t = t0 + g*8 + 4*hi + (0..3), guarded j ----
    if (j < NUM_D1) {
      #pragma unroll
      for (int g = 0; g < 4; ++g) {
        f32x4 v4;
        v4[0] = acc[g * 4 + 0]; v4[1] = acc[g * 4 + 1];
        v4[2] = acc[g * 4 + 2]; v4[3] = acc[g * 4 + 3];
        *(f32x4*)(orow_base + t0 + g * 8) = v4;
      }
    }

    if (it < 15) {
      // wait for the 4 prefetch loads (newest 4 VMEM ops are this iter's stores)
      asm volatile("s_waitcnt vmcnt(4)" ::: "memory");
      __builtin_amdgcn_sched_barrier(0);
      #pragma unroll
      for (int f = 0; f < 4; ++f) {
        uint2 w;
        w.x = cvt_pk_bf16(va[0][f], va[1][f]);
        w.y = cvt_pk_bf16(va[2][f], va[3][f]);
        *(uint2*)(xnxt + (t4 * 4 + f) * ROWB + c4 * 8) = w;
      }
      if (it < 14) {
        #pragma unroll
        for (int e = 0; e < 4; ++e) {
          int c = c4 * 4 + e;
          if (c < NUM_C) va[e] = *(const f32x4*)(Xb + (size_t)c * NUM_T + t0 + 64 + t4 * 4);
          else { va[e][0] = va[e][1] = va[e][2] = va[e][3] = 0.f; }
        }
      }
      FENCED_BARRIER();
    }
  }
}

extern "C" void kernel_launch(void* const* d_in, const int* in_sizes, int n_in,
                              void* d_out, int out_size, void* d_ws, size_t ws_size,
                              hipStream_t stream) {
  const float* X   = (const float*)d_in[0];
  const float* loc = (const float*)d_in[1];
  const float* zre = (const float*)d_in[2];
  const float* zim = (const float*)d_in[3];
  float* out = (float*)d_out;
  char* ws = (char*)d_ws;
  float2* tab = (float2*)(ws);                              // 2,621,440 B
  float* a    = (float*)(ws + 2621440);                     // 313,344 B
  unsigned short* wgp = (unsigned short*)(ws + 2934784);    // [288][292] bf16 = 168,192 B

  (void)hipFuncSetAttribute((const void*)k_out7,
                            hipFuncAttributeMaxDynamicSharedMemorySize, LDS7_TOTAL);

  hipLaunchKernelGGL(k_trig,    dim3(1280),   dim3(256),  0, stream, loc, tab);
  hipLaunchKernelGGL(k_agemm,   dim3(68, 5),  dim3(1024), 0, stream, zre, zim, tab, a);
  hipLaunchKernelGGL(k_softmax, dim3(72),     dim3(256),  0, stream, a, wgp);
  hipLaunchKernelGGL(k_out7,    dim3(256),    dim3(576),  LDS7_TOTAL, stream, X, wgp, out);
}

// Round 12
// 163.624 us; speedup vs baseline: 1.2516x; 1.1182x over previous
//
#include <hip/hip_runtime.h>
#include <hip/hip_bf16.h>

#define NUM_D1 270
#define NUM_B  128
#define NUM_C  273
#define NUM_T  1024
#define KL     1024      // K*K = 32*32
#define TW     320       // trig table padded width
#define CP     288       // padded C for a[] (9 * 32)
#define CW     292       // wg / X-LDS row stride in elems (584 B = 146 dw == 18 mod 32; 2-way free)
#define ROWB   (CW * 2)  // 584 bytes

#define XT_BYTES (32 * ROWB)        // 18,688  (one 32-t X^T tile)
#define LDS8_TOTAL (2 * XT_BYTES)   // 37,376

typedef float f32x4 __attribute__((ext_vector_type(4)));
typedef float f32x16 __attribute__((ext_vector_type(16)));
typedef __bf16 bf16x8 __attribute__((ext_vector_type(8)));

// Barrier with compiler memory fences on BOTH sides (r8's replay race fix).
#define FENCED_BARRIER()                                     \
  do {                                                       \
    asm volatile("s_waitcnt lgkmcnt(0)" ::: "memory");       \
    __builtin_amdgcn_s_barrier();                            \
    asm volatile("" ::: "memory");                           \
    __builtin_amdgcn_sched_barrier(0);                       \
  } while (0)

static __device__ __forceinline__ unsigned short f2bf(float f) {
  unsigned u = __float_as_uint(f);
  unsigned r = (u + 0x7fffu + ((u >> 16) & 1u)) >> 16;   // RNE
  return (unsigned short)r;
}

static __device__ __forceinline__ unsigned cvt_pk_bf16(float lo, float hi) {
  unsigned r;
  asm("v_cvt_pk_bf16_f32 %0, %1, %2" : "=v"(r) : "v"(lo), "v"(hi));
  return r;
}

// Kernel 0: trig table (cos,sin) interleaved float2
__global__ __launch_bounds__(256) void k_trig(const float* __restrict__ loc,
                                              float2* __restrict__ tab) {
  int idx = blockIdx.x * 256 + threadIdx.x;   // 0 .. 1024*320-1
  int kl = idx / TW;
  int c  = idx - kl * TW;
  float cv = 0.f, sv = 0.f;
  if (c < NUM_C) {
    float x = loc[2 * c], y = loc[2 * c + 1];
    float kf = (float)(kl >> 5), lf = (float)(kl & 31);
    float ph = 6.283185307179586f * (kf * x + lf * y);
    sincosf(ph, &sv, &cv);
  }
  tab[idx] = make_float2(cv, sv);
}

// Kernel 1: a[j,c] = sum_kl z_re[j,kl]*cos[kl,c] + z_im[j,kl]*sin[kl,c]
__global__ __launch_bounds__(1024) void k_agemm(const float* __restrict__ z_re,
                                                const float* __restrict__ z_im,
                                                const float2* __restrict__ tab,
                                                float* __restrict__ a) {
  __shared__ float sm[4][8][64];
  int tid = threadIdx.x;
  int lane = tid & 63;
  int g = tid >> 6;            // 0..15
  int p = g >> 3;              // 0..1
  int q = g & 7;               // 0..7
  int jb = blockIdx.x;         // 0..67
  int cb = blockIdx.y;         // 0..4
  int c = cb * 64 + lane;      // < 320, in-bounds of padded table
  int j_a = jb * 4 + p;        // <= 269
  int j_b = j_a + 2;           // <= 271
  int jeb = (j_b < NUM_D1) ? j_b : 0;
  const float* zr0 = z_re + (size_t)j_a * KL;
  const float* zi0 = z_im + (size_t)j_a * KL;
  const float* zr1 = z_re + (size_t)jeb * KL;
  const float* zi1 = z_im + (size_t)jeb * KL;
  float a0 = 0.f, a1 = 0.f;
  int k0 = q * 128;
  #pragma unroll 4
  for (int kk = k0; kk < k0 + 128; ++kk) {
    float2 cs = tab[kk * TW + c];
    a0 = fmaf(zr0[kk], cs.x, a0);
    a0 = fmaf(zi0[kk], cs.y, a0);
    a1 = fmaf(zr1[kk], cs.x, a1);
    a1 = fmaf(zi1[kk], cs.y, a1);
  }
  sm[p][q][lane] = a0;
  sm[p + 2][q][lane] = a1;
  __syncthreads();
  if (tid < 256) {
    int jl = tid >> 6;          // 0..3
    int l2 = tid & 63;
    int j = jb * 4 + jl;
    int c2 = cb * 64 + l2;
    float s = 0.f;
    #pragma unroll
    for (int qq = 0; qq < 8; ++qq) s += sm[jl][qq][l2];
    if (j < NUM_D1 && c2 < NUM_C) a[j * CP + c2] = s;
  }
}

// Kernel 2: w[j,:] = softmax_c(a[j,:]) -> bf16 into wg[288 rows][CW=292 stride], zero-padded
__global__ __launch_bounds__(256) void k_softmax(const float* __restrict__ a,
                                                 unsigned short* __restrict__ wg) {
  int wv = threadIdx.x >> 6;
  int lane = threadIdx.x & 63;
  int j = blockIdx.x * 4 + wv;   // < 288 (grid 72)
  if (j >= NUM_D1) {
    for (int c = lane; c < CW; c += 64) wg[j * CW + c] = 0;
    return;
  }
  float e[5];
  float s = 0.f;
  #pragma unroll
  for (int qq = 0; qq < 5; ++qq) {
    int c = qq * 64 + lane;
    float v = 0.f;
    if (c < NUM_C) v = expf(a[j * CP + c]);
    e[qq] = v;
    s += v;
  }
  #pragma unroll
  for (int o = 32; o > 0; o >>= 1) s += __shfl_xor(s, o, 64);
  float inv = 1.0f / s;
  #pragma unroll
  for (int qq = 0; qq < 5; ++qq) {
    int c = qq * 64 + lane;
    if (c < CW) wg[j * CW + c] = (c < NUM_C) ? f2bf(e[qq] * inv) : (unsigned short)0;
  }
}

// Kernel 3 (k_out8): 32x32x16 MFMA, W register-resident, A=W B=X so that
// D col = lane&31 = t (coalesced stores), row = (reg&3)+8*(reg>>2)+4*(lane>>5) = j.
// 576 thr / 9 waves; wave wv owns j32-tile wv. LDS = double-buffered 32t x 288c
// X^T tile. Grid (2 t-halves x 128 b). One-ahead prefetch, loads-first order,
// vmcnt(16) never blocks on stores, nontemporal full-line output stores.
__global__ __launch_bounds__(576) void k_out8(const float* __restrict__ X,
                                              const unsigned short* __restrict__ wg,
                                              float* __restrict__ out) {
  extern __shared__ char lds[];
  char* XA  = lds;
  char* XB2 = lds + XT_BYTES;

  const int tid = threadIdx.x;
  const int wv = tid / 64, lane = tid & 63;
  const int nlo = lane & 31, hi = lane >> 5;
  const int th = blockIdx.x >> 7;       // 0..1 (t-half)
  const int b  = blockIdx.x & 127;      // 0..127
  const int tbase = th * 512;
  const float* Xb = X + (size_t)b * (NUM_C * NUM_T);

  // staging geometry: c-quad c4 = tid>>3 (0..71), t-quad t4 = tid&7
  const int c4 = tid >> 3;
  const int t4 = tid & 7;

  // ---- W fragments (A operand), once per block: row j = wv*32 + nlo,
  //      k = ks*16 + hi*8 + (0..7)  -> byte ks*32 + hi*16
  bf16x8 wfr[18];
  {
    const char* wrow = (const char*)wg + (size_t)(wv * 32 + nlo) * ROWB + hi * 16;
    #pragma unroll
    for (int ks = 0; ks < 18; ++ks) {
      wfr[ks] = *(const bf16x8*)(wrow + ks * 32);
      asm volatile("" : "+v"(wfr[ks]));   // opaque def: cannot be sunk/rematerialized
    }
  }

  f32x4 va[4];

  // ---- prologue: tile 0 load -> write XA ----
  #pragma unroll
  for (int e = 0; e < 4; ++e) {
    int c = c4 * 4 + e;
    if (c < NUM_C) va[e] = *(const f32x4*)(Xb + (size_t)c * NUM_T + tbase + t4 * 4);
    else { va[e][0] = va[e][1] = va[e][2] = va[e][3] = 0.f; }
  }
  #pragma unroll
  for (int f = 0; f < 4; ++f) {
    uint2 w;
    w.x = cvt_pk_bf16(va[0][f], va[1][f]);
    w.y = cvt_pk_bf16(va[2][f], va[3][f]);
    *(uint2*)(XA + (t4 * 4 + f) * ROWB + c4 * 8) = w;
  }
  FENCED_BARRIER();

  for (int it = 0; it < 16; ++it) {
    const int t0 = tbase + it * 32;
    char* xcur = (it & 1) ? XB2 : XA;
    char* xnxt = (it & 1) ? XA : XB2;

    // 1) issue next tile's 4 global loads FIRST (latency hides under compute)
    if (it < 15) {
      #pragma unroll
      for (int e = 0; e < 4; ++e) {
        int c = c4 * 4 + e;
        if (c < NUM_C) va[e] = *(const f32x4*)(Xb + (size_t)c * NUM_T + t0 + 32 + t4 * 4);
        else { va[e][0] = va[e][1] = va[e][2] = va[e][3] = 0.f; }
      }
      __builtin_amdgcn_sched_barrier(0);
    }

    // 2) compute: 18 ds_read_b128 + 18 MFMA, dual accumulators (2-way chain ILP)
    f32x16 ac0, ac1;
    #pragma unroll
    for (int r = 0; r < 16; ++r) { ac0[r] = 0.f; ac1[r] = 0.f; }
    const char* xrow = xcur + (size_t)nlo * ROWB + hi * 16;
    #pragma unroll
    for (int ks = 0; ks < 9; ++ks) {
      bf16x8 x0 = *(const bf16x8*)(xrow + (2 * ks) * 32);
      bf16x8 x1 = *(const bf16x8*)(xrow + (2 * ks + 1) * 32);
      ac0 = __builtin_amdgcn_mfma_f32_32x32x16_bf16(wfr[2 * ks], x0, ac0, 0, 0, 0);
      ac1 = __builtin_amdgcn_mfma_f32_32x32x16_bf16(wfr[2 * ks + 1], x1, ac1, 0, 0, 0);
    }

    // 3) stores: 16 NT dwords; lanes cover t contiguously (2 full 128B runs/instr)
    {
      const size_t obase = (size_t)b * NUM_D1 * NUM_T + t0 + nlo;
      #pragma unroll
      for (int r = 0; r < 16; ++r) {
        int m = (r & 3) + 8 * (r >> 2) + 4 * hi;
        int j = wv * 32 + m;
        if (j < NUM_D1)
          __builtin_nontemporal_store(ac0[r] + ac1[r], out + obase + (size_t)j * NUM_T);
      }
    }

    if (it < 15) {
      // 4) wait for the 4 prefetch loads only (16 newer stores may linger)
      asm volatile("s_waitcnt vmcnt(16)" ::: "memory");
      __builtin_amdgcn_sched_barrier(0);
      #pragma unroll
      for (int f = 0; f < 4; ++f) {
        uint2 w;
        w.x = cvt_pk_bf16(va[0][f], va[1][f]);
        w.y = cvt_pk_bf16(va[2][f], va[3][f]);
        *(uint2*)(xnxt + (t4 * 4 + f) * ROWB + c4 * 8) = w;
      }
      FENCED_BARRIER();
    }
  }
}

extern "C" void kernel_launch(void* const* d_in, const int* in_sizes, int n_in,
                              void* d_out, int out_size, void* d_ws, size_t ws_size,
                              hipStream_t stream) {
  const float* X   = (const float*)d_in[0];
  const float* loc = (const float*)d_in[1];
  const float* zre = (const float*)d_in[2];
  const float* zim = (const float*)d_in[3];
  float* out = (float*)d_out;
  char* ws = (char*)d_ws;
  float2* tab = (float2*)(ws);                              // 2,621,440 B
  float* a    = (float*)(ws + 2621440);                     // 313,344 B
  unsigned short* wgp = (unsigned short*)(ws + 2934784);    // [288][292] bf16 = 168,192 B

  (void)hipFuncSetAttribute((const void*)k_out8,
                            hipFuncAttributeMaxDynamicSharedMemorySize, LDS8_TOTAL);

  hipLaunchKernelGGL(k_trig,    dim3(1280),   dim3(256),  0, stream, loc, tab);
  hipLaunchKernelGGL(k_agemm,   dim3(68, 5),  dim3(1024), 0, stream, zre, zim, tab, a);
  hipLaunchKernelGGL(k_softmax, dim3(72),     dim3(256),  0, stream, a, wgp);
  hipLaunchKernelGGL(k_out8,    dim3(256),    dim3(576),  LDS8_TOTAL, stream, X, wgp, out);
}